// Round 8
// baseline (2631.477 us; speedup 1.0000x reference)
//
#include <hip/hip_runtime.h>
#include <hip/hip_fp16.h>

#define TSEQ   2048
#define NB     64
#define NE     256
#define NH     256
#define NG     768
#define TCH    64
#define NCHUNK (TSEQ / TCH)
#define POOL_BYTES 87552

// ---------------------------------------------------------------------------
// Pack w_hh into the per-thread-contiguous fp16 layout consumed by the asm
// loop: thread (j, s) owns 768 B at byte offset (j*2+s)*768:
//   [g in {r,z,n}][i in 0..15] quad (16 B) ; quad u32 c = fp16 pair of
//   whh[(g*256 + j)][ s*128 + i*8 + 2c , +1 ].
// ---------------------------------------------------------------------------
__global__ void prep_whh(const float* __restrict__ whh, unsigned int* __restrict__ w16) {
  int idx = blockIdx.x * 256 + threadIdx.x;        // u32 index, 0..98303
  if (idx >= 98304) return;
  int c  = idx & 3;
  int i  = (idx >> 2) & 15;
  int g  = (idx >> 6) % 3;
  int js = idx / 192;
  int s  = js & 1;
  int j  = js >> 1;
  int k  = s * 128 + i * 8 + 2 * c;
  const float* src = whh + (size_t)(g * 256 + j) * 256 + k;
  union { struct { _Float16 a, b; } h; unsigned int u; } cvt;
  cvt.h.a = (_Float16)src[0];
  cvt.h.b = (_Float16)src[1];
  w16[idx] = cvt.u;
}

// ---- asm building blocks ---------------------------------------------------
#define DOT12(H0,H1,H2,H3,R0,R1,R2,R3,Z0,Z1,Z2,Z3,N0,N1,N2,N3) \
  "v_dot2_f32_f16 v16, v" H0 ", v" R0 ", v16\n\t" \
  "v_dot2_f32_f16 v17, v" H0 ", v" Z0 ", v17\n\t" \
  "v_dot2_f32_f16 v18, v" H0 ", v" N0 ", v18\n\t" \
  "v_dot2_f32_f16 v16, v" H1 ", v" R1 ", v16\n\t" \
  "v_dot2_f32_f16 v17, v" H1 ", v" Z1 ", v17\n\t" \
  "v_dot2_f32_f16 v18, v" H1 ", v" N1 ", v18\n\t" \
  "v_dot2_f32_f16 v16, v" H2 ", v" R2 ", v16\n\t" \
  "v_dot2_f32_f16 v17, v" H2 ", v" Z2 ", v17\n\t" \
  "v_dot2_f32_f16 v18, v" H2 ", v" N2 ", v18\n\t" \
  "v_dot2_f32_f16 v16, v" H3 ", v" R3 ", v16\n\t" \
  "v_dot2_f32_f16 v17, v" H3 ", v" Z3 ", v17\n\t" \
  "v_dot2_f32_f16 v18, v" H3 ", v" N3 ", v18\n\t"

// tail: reduce halves, gates, write h, barrier.  CA* = gi regs consumed,
// WOF = h write offset (other buffer).  vmcnt(3) leaves next-step gi in flight.
#define TAIL(CA0,CA1,CA2,WOF) \
  "ds_bpermute_b32 v20, v19, v16\n\t" \
  "ds_bpermute_b32 v21, v19, v17\n\t" \
  "ds_bpermute_b32 v22, v19, v18\n\t" \
  "s_waitcnt lgkmcnt(0)\n\t" \
  "v_add_f32 v16, v16, v20\n\t" \
  "v_add_f32 v17, v17, v21\n\t" \
  "v_add_f32 v18, v18, v22\n\t" \
  "s_waitcnt vmcnt(3)\n\t" \
  "v_add_f32 v20, v" CA0 ", v16\n\t" \
  "v_mul_f32 v20, 0xbfb8aa3b, v20\n\t" \
  "v_exp_f32 v20, v20\n\t" \
  "s_nop 0\n\t" \
  "v_add_f32 v20, 1.0, v20\n\t" \
  "v_rcp_f32 v20, v20\n\t" \
  "s_nop 0\n\t" \
  "v_add_f32 v21, v" CA1 ", v17\n\t" \
  "v_mul_f32 v21, 0xbfb8aa3b, v21\n\t" \
  "v_exp_f32 v21, v21\n\t" \
  "s_nop 0\n\t" \
  "v_add_f32 v21, 1.0, v21\n\t" \
  "v_rcp_f32 v21, v21\n\t" \
  "s_nop 0\n\t" \
  "v_add_f32 v22, v18, v28\n\t" \
  "v_fma_f32 v22, v20, v22, v" CA2 "\n\t" \
  "v_min_f32 v22, 0x41700000, v22\n\t" \
  "v_mul_f32 v22, 0x4038aa3b, v22\n\t" \
  "v_exp_f32 v22, v22\n\t" \
  "s_nop 0\n\t" \
  "v_add_f32 v23, -1.0, v22\n\t" \
  "v_add_f32 v22, 1.0, v22\n\t" \
  "v_rcp_f32 v22, v22\n\t" \
  "s_nop 0\n\t" \
  "v_mul_f32 v22, v23, v22\n\t" \
  "v_sub_f32 v23, v24, v22\n\t" \
  "v_fma_f32 v24, v21, v23, v22\n\t" \
  "v_cvt_f16_f32 v25, v24\n\t" \
  "ds_write_b16 v29, v25 offset:" WOF "\n\t" \
  "s_waitcnt lgkmcnt(0)\n\t" \
  "s_barrier\n\t"

// one timestep: 8-deep LDS pipeline (staging v32-v63), gi prefetch for next
// step into PB*, consume CA* (loaded one step earlier).
#define STEP(O0,O1,O2,O3,O4,O5,O6,O7,O8,O9,O10,O11,O12,O13,O14,O15,CA0,CA1,CA2,PB0,PB1,PB2,WOF) \
  "ds_read_b128 v[32:35], v2 offset:" O0 "\n\t" \
  "ds_read_b128 v[36:39], v2 offset:" O1 "\n\t" \
  "ds_read_b128 v[40:43], v2 offset:" O2 "\n\t" \
  "ds_read_b128 v[44:47], v2 offset:" O3 "\n\t" \
  "ds_read_b128 v[48:51], v2 offset:" O4 "\n\t" \
  "ds_read_b128 v[52:55], v2 offset:" O5 "\n\t" \
  "ds_read_b128 v[56:59], v2 offset:" O6 "\n\t" \
  "ds_read_b128 v[60:63], v2 offset:" O7 "\n\t" \
  "global_load_dword v" PB0 ", v3, %[gip]\n\t" \
  "global_load_dword v" PB1 ", v3, %[gip] offset:1024\n\t" \
  "global_load_dword v" PB2 ", v3, %[gip] offset:2048\n\t" \
  "v_add_u32 v3, 0x30000, v3\n\t" \
  "v_mov_b32 v16, 0\n\t" \
  "v_mov_b32 v17, 0\n\t" \
  "v_mov_b32 v18, 0\n\t" \
  "s_waitcnt lgkmcnt(7)\n\t" \
  DOT12("32","33","34","35","64","65","66","67","128","129","130","131","192","193","194","195") \
  "ds_read_b128 v[32:35], v2 offset:" O8 "\n\t" \
  "s_waitcnt lgkmcnt(7)\n\t" \
  DOT12("36","37","38","39","68","69","70","71","132","133","134","135","196","197","198","199") \
  "ds_read_b128 v[36:39], v2 offset:" O9 "\n\t" \
  "s_waitcnt lgkmcnt(7)\n\t" \
  DOT12("40","41","42","43","72","73","74","75","136","137","138","139","200","201","202","203") \
  "ds_read_b128 v[40:43], v2 offset:" O10 "\n\t" \
  "s_waitcnt lgkmcnt(7)\n\t" \
  DOT12("44","45","46","47","76","77","78","79","140","141","142","143","204","205","206","207") \
  "ds_read_b128 v[44:47], v2 offset:" O11 "\n\t" \
  "s_waitcnt lgkmcnt(7)\n\t" \
  DOT12("48","49","50","51","80","81","82","83","144","145","146","147","208","209","210","211") \
  "ds_read_b128 v[48:51], v2 offset:" O12 "\n\t" \
  "s_waitcnt lgkmcnt(7)\n\t" \
  DOT12("52","53","54","55","84","85","86","87","148","149","150","151","212","213","214","215") \
  "ds_read_b128 v[52:55], v2 offset:" O13 "\n\t" \
  "s_waitcnt lgkmcnt(7)\n\t" \
  DOT12("56","57","58","59","88","89","90","91","152","153","154","155","216","217","218","219") \
  "ds_read_b128 v[56:59], v2 offset:" O14 "\n\t" \
  "s_waitcnt lgkmcnt(7)\n\t" \
  DOT12("60","61","62","63","92","93","94","95","156","157","158","159","220","221","222","223") \
  "ds_read_b128 v[60:63], v2 offset:" O15 "\n\t" \
  "s_waitcnt lgkmcnt(7)\n\t" \
  DOT12("32","33","34","35","96","97","98","99","160","161","162","163","224","225","226","227") \
  "s_waitcnt lgkmcnt(6)\n\t" \
  DOT12("36","37","38","39","100","101","102","103","164","165","166","167","228","229","230","231") \
  "s_waitcnt lgkmcnt(5)\n\t" \
  DOT12("40","41","42","43","104","105","106","107","168","169","170","171","232","233","234","235") \
  "s_waitcnt lgkmcnt(4)\n\t" \
  DOT12("44","45","46","47","108","109","110","111","172","173","174","175","236","237","238","239") \
  "s_waitcnt lgkmcnt(3)\n\t" \
  DOT12("48","49","50","51","112","113","114","115","176","177","178","179","240","241","242","243") \
  "s_waitcnt lgkmcnt(2)\n\t" \
  DOT12("52","53","54","55","116","117","118","119","180","181","182","183","244","245","246","247") \
  "s_waitcnt lgkmcnt(1)\n\t" \
  DOT12("56","57","58","59","120","121","122","123","184","185","186","187","248","249","250","251") \
  "s_waitcnt lgkmcnt(0)\n\t" \
  DOT12("60","61","62","63","124","125","126","127","188","189","190","191","252","253","254","255") \
  TAIL(CA0,CA1,CA2,WOF)

#define WLD(D0,D1,OFF) \
  "global_load_dwordx4 v[" D0 ":" D1 "], %[wof], %[wptr] offset:" OFF "\n\t"

// ---------------------------------------------------------------------------
// Fused per-chunk kernel, 512 threads.
//   blocks [0, rec_count)            : recurrence (1 block = 1 batch element)
//   blocks [rec_count, rec_count+192): gi GEMM for the NEXT chunk
// rec inner loop is hand-written asm; weights pinned in v[64:255], h-quad
// staging 8-deep in v[32:63], gi prefetched one step ahead (A/B reg sets).
// ---------------------------------------------------------------------------
__global__ __launch_bounds__(512)
void fused_kernel(const int* __restrict__ seq, const float* __restrict__ emb,
                  const float* __restrict__ wih, const float* __restrict__ bih,
                  const float* __restrict__ bhh, const unsigned int* __restrict__ w16,
                  const float* __restrict__ rec_gi, float* __restrict__ gi_dst,
                  int gi_t0, float* __restrict__ h_state, float* __restrict__ out,
                  int rec_count, int chunk)
{
  __shared__ __align__(16) char smem[POOL_BYTES];
  const int tid = threadIdx.x;

  if ((int)blockIdx.x < rec_count) {
    // ======================= recurrence (asm) =======================
    const int b = blockIdx.x;
    const unsigned lane = tid & 63;
    const unsigned jj   = (unsigned)(tid >> 6) * 32 + (lane & 31);
    const unsigned sh   = lane >> 5;

    float h0 = 0.f;
    if (chunk != 0) h0 = h_state[b * NH + jj];
    const float bnv = bhh[2 * NH + jj];
    ((_Float16*)smem)[jj] = (_Float16)h0;   // h buffer 0 (dup same-value writes OK)
    __syncthreads();

    const unsigned pool0 = (unsigned)(uintptr_t)(smem);
    const unsigned hrd = pool0 + sh * 256;         // h read base (+ s-half)
    const unsigned hwa = pool0 + jj * 2;           // h write addr (b16)
    const unsigned gio = jj * 4;                   // gi byte offset
    const unsigned bpa = (lane ^ 32u) << 2;        // bpermute partner addr
    const unsigned wof = (jj * 2 + sh) * 768;      // weight block byte offset
    const float* gib = rec_gi + (size_t)b * NG;

    float hout;
    asm volatile(
      "v_mov_b32 v2, %[hrd]\n\t"
      "v_mov_b32 v3, %[gio]\n\t"
      "v_mov_b32 v19, %[bpa]\n\t"
      "v_mov_b32 v24, %[h0]\n\t"
      "v_mov_b32 v28, %[bn]\n\t"
      "v_mov_b32 v29, %[hwa]\n\t"
      WLD("64","67","0")    WLD("68","71","16")   WLD("72","75","32")   WLD("76","79","48")
      WLD("80","83","64")   WLD("84","87","80")   WLD("88","91","96")   WLD("92","95","112")
      WLD("96","99","128")  WLD("100","103","144")WLD("104","107","160")WLD("108","111","176")
      WLD("112","115","192")WLD("116","119","208")WLD("120","123","224")WLD("124","127","240")
      WLD("128","131","256")WLD("132","135","272")WLD("136","139","288")WLD("140","143","304")
      WLD("144","147","320")WLD("148","151","336")WLD("152","155","352")WLD("156","159","368")
      WLD("160","163","384")WLD("164","167","400")WLD("168","171","416")WLD("172","175","432")
      WLD("176","179","448")WLD("180","183","464")WLD("184","187","480")WLD("188","191","496")
      WLD("192","195","512")WLD("196","199","528")WLD("200","203","544")WLD("204","207","560")
      WLD("208","211","576")WLD("212","215","592")WLD("216","219","608")WLD("220","223","624")
      WLD("224","227","640")WLD("228","231","656")WLD("232","235","672")WLD("236","239","688")
      WLD("240","243","704")WLD("244","247","720")WLD("248","251","736")WLD("252","255","752")
      "s_waitcnt vmcnt(0)\n\t"
      // gi for step 0 -> A regs (v12,v13,v14)
      "global_load_dword v12, v3, %[gip]\n\t"
      "global_load_dword v13, v3, %[gip] offset:1024\n\t"
      "global_load_dword v14, v3, %[gip] offset:2048\n\t"
      "v_add_u32 v3, 0x30000, v3\n\t"
      "s_mov_b32 s20, 32\n\t"
      "1:\n\t"
      // even step: read h buf0, consume gi A, prefetch gi B, write h buf1
      STEP("0","16","32","48","64","80","96","112",
           "128","144","160","176","192","208","224","240",
           "12","13","14","26","27","30","512")
      // odd step: read h buf1, consume gi B, prefetch gi A, write h buf0
      STEP("512","528","544","560","576","592","608","624",
           "640","656","672","688","704","720","736","752",
           "26","27","30","12","13","14","0")
      "s_sub_u32 s20, s20, 1\n\t"
      "s_cmp_lg_u32 s20, 0\n\t"
      "s_cbranch_scc1 1b\n\t"
      "v_mov_b32 %[hout], v24\n\t"
      : [hout] "=v"(hout)
      : [hrd] "v"(hrd), [gio] "v"(gio), [bpa] "v"(bpa), [h0] "v"(h0),
        [bn] "v"(bnv), [hwa] "v"(hwa), [wof] "v"(wof),
        [wptr] "s"(w16), [gip] "s"(gib)
      : "memory","scc","s20",
        "v2","v3","v12","v13","v14","v16","v17","v18","v19","v20","v21","v22",
        "v23","v24","v25","v26","v27","v28","v29","v30",
        "v32","v33","v34","v35","v36","v37","v38","v39","v40","v41","v42","v43",
        "v44","v45","v46","v47","v48","v49","v50","v51","v52","v53","v54","v55",
        "v56","v57","v58","v59","v60","v61","v62","v63",
        "v64","v65","v66","v67","v68","v69","v70","v71","v72","v73","v74","v75",
        "v76","v77","v78","v79","v80","v81","v82","v83","v84","v85","v86","v87",
        "v88","v89","v90","v91","v92","v93","v94","v95","v96","v97","v98","v99",
        "v100","v101","v102","v103","v104","v105","v106","v107","v108","v109",
        "v110","v111","v112","v113","v114","v115","v116","v117","v118","v119",
        "v120","v121","v122","v123","v124","v125","v126","v127","v128","v129",
        "v130","v131","v132","v133","v134","v135","v136","v137","v138","v139",
        "v140","v141","v142","v143","v144","v145","v146","v147","v148","v149",
        "v150","v151","v152","v153","v154","v155","v156","v157","v158","v159",
        "v160","v161","v162","v163","v164","v165","v166","v167","v168","v169",
        "v170","v171","v172","v173","v174","v175","v176","v177","v178","v179",
        "v180","v181","v182","v183","v184","v185","v186","v187","v188","v189",
        "v190","v191","v192","v193","v194","v195","v196","v197","v198","v199",
        "v200","v201","v202","v203","v204","v205","v206","v207","v208","v209",
        "v210","v211","v212","v213","v214","v215","v216","v217","v218","v219",
        "v220","v221","v222","v223","v224","v225","v226","v227","v228","v229",
        "v230","v231","v232","v233","v234","v235","v236","v237","v238","v239",
        "v240","v241","v242","v243","v244","v245","v246","v247","v248","v249",
        "v250","v251","v252","v253","v254","v255");

    h_state[b * NH + jj] = hout;
    if (out) out[b * NH + jj] = hout;
  } else {
    // ======================= gi GEMM ==========================
    if (gi_dst == nullptr) return;
    float (*xs)[68]  = (float(*)[68])smem;                 // 17,408 B
    float (*wsh)[68] = (float(*)[68])(smem + 17408);       // 69,632 B
    int*  tok        = (int*)(smem + 17408 + 69632);       //    256 B
    const int gb = blockIdx.x - rec_count;   // 0..191
    const int tl = gb & 63;                  // local timestep
    const int g0 = (gb >> 6) * 256;          // gate-column region
    const int t  = gi_t0 + tl;
    if (tid < 64) tok[tid] = seq[tid * TSEQ + t];
    const int tx = tid & 31;                 // 32 col groups
    const int ty = tid >> 5;                 // 16 row groups of 4
    float acc[4][8];
#pragma unroll
    for (int i = 0; i < 4; ++i)
#pragma unroll
      for (int c8 = 0; c8 < 8; ++c8) acc[i][c8] = 0.f;

    for (int kb = 0; kb < 4; ++kb) {
      __syncthreads();                       // covers tok on first iter
#pragma unroll
      for (int it = 0; it < 2; ++it) {
        int i = it * 512 + tid;
        int r = i >> 4, c = i & 15;
        *(float4*)(&xs[r][c * 4]) =
            *(const float4*)(emb + (size_t)tok[r] * NE + kb * 64 + c * 4);
      }
#pragma unroll
      for (int it = 0; it < 8; ++it) {
        int i = it * 512 + tid;
        int r = i >> 4, c = i & 15;
        *(float4*)(&wsh[r][c * 4]) =
            *(const float4*)(wih + (size_t)(g0 + r) * NE + kb * 64 + c * 4);
      }
      __syncthreads();
#pragma unroll 4
      for (int k4 = 0; k4 < 16; ++k4) {
        float4 xf[4], wf[8];
#pragma unroll
        for (int i = 0; i < 4; ++i) xf[i] = *(const float4*)(&xs[ty * 4 + i][k4 * 4]);
#pragma unroll
        for (int c8 = 0; c8 < 8; ++c8) wf[c8] = *(const float4*)(&wsh[tx + 32 * c8][k4 * 4]);
#pragma unroll
        for (int i = 0; i < 4; ++i)
#pragma unroll
          for (int c8 = 0; c8 < 8; ++c8)
            acc[i][c8] += xf[i].x * wf[c8].x + xf[i].y * wf[c8].y +
                          xf[i].z * wf[c8].z + xf[i].w * wf[c8].w;
      }
    }
#pragma unroll
    for (int i = 0; i < 4; ++i) {
      const int brow = ty * 4 + i;
      float* dst = gi_dst + ((size_t)(tl * NB + brow)) * NG + g0;
#pragma unroll
      for (int c8 = 0; c8 < 8; ++c8) {
        const int col = tx + 32 * c8;
        const int g = g0 + col;
        float bias = bih[g] + (g < 2 * NH ? bhh[g] : 0.f);
        dst[col] = acc[i][c8] + bias;
      }
    }
  }
}

extern "C" void kernel_launch(void* const* d_in, const int* in_sizes, int n_in,
                              void* d_out, int out_size, void* d_ws, size_t ws_size,
                              hipStream_t stream) {
  (void)in_sizes; (void)n_in; (void)out_size; (void)ws_size;
  const int*   seq = (const int*)d_in[0];
  const float* emb = (const float*)d_in[1];
  const float* wih = (const float*)d_in[2];
  const float* whh = (const float*)d_in[3];
  const float* bih = (const float*)d_in[4];
  const float* bhh = (const float*)d_in[5];
  float* out = (float*)d_out;
  char*  ws  = (char*)d_ws;

  unsigned int* w16     = (unsigned int*)(ws);            // 393,216 B
  float*        h_state = (float*)(ws + 393216);          //  65,536 B
  float*        gi0     = (float*)(ws + 458752);          // 12,582,912 B
  float*        gi1     = (float*)(ws + 458752 + 12582912);
  // + 256 KB pad after gi1 for the last-step gi prefetch overshoot

  prep_whh<<<dim3(384), dim3(256), 0, stream>>>(whh, w16);

  // prologue: gi for chunk 0 only
  fused_kernel<<<dim3(192), dim3(512), 0, stream>>>(
      seq, emb, wih, bih, bhh, w16,
      nullptr, gi0, 0, h_state, nullptr, 0, 0);

  for (int c = 0; c < NCHUNK; ++c) {
    float* rd  = (c & 1) ? gi1 : gi0;
    float* wr_ = (c & 1) ? gi0 : gi1;
    const bool last = (c == NCHUNK - 1);
    const int grid  = last ? NB : NB + 192;
    fused_kernel<<<dim3(grid), dim3(512), 0, stream>>>(
        seq, emb, wih, bih, bhh, w16,
        rd, last ? nullptr : wr_, (c + 1) * TCH, h_state,
        last ? out : nullptr, NB, c);
  }
}